// Round 10
// baseline (164.476 us; speedup 1.0000x reference)
//
#include <hip/hip_runtime.h>

typedef unsigned short u16;
typedef __attribute__((ext_vector_type(4)))  float f32x4;
typedef __attribute__((ext_vector_type(16))) float f32x16;
typedef __attribute__((ext_vector_type(8)))  short s16x8;   // 8 bf16 MFMA fragment
typedef __attribute__((ext_vector_type(4)))  unsigned short u16x4;
typedef __attribute__((ext_vector_type(8)))  unsigned short u16x8;

typedef const __attribute__((address_space(1))) void* gp1;
typedef __attribute__((address_space(3))) void* lp3;
#define GLOAD16(g, l) __builtin_amdgcn_global_load_lds((gp1)(g), (lp3)(l), 16, 0, 0)

__device__ __forceinline__ u16 f2bf(float f) {
    union { float f; unsigned u; } c; c.f = f;
    unsigned r = c.u + 0x7fffu + ((c.u >> 16) & 1u);   // RNE
    return (u16)(r >> 16);
}

// ---------------- fp32 -> bf16 cast (all 5 arrays, one launch) ----------------
__global__ void castall(const float* __restrict__ x,  const float* __restrict__ wq,
                        const float* __restrict__ wk, const float* __restrict__ wv,
                        const float* __restrict__ wp,
                        u16* __restrict__ xb,  u16* __restrict__ wqb, u16* __restrict__ wkb,
                        u16* __restrict__ wvb, u16* __restrict__ wpb) {
    int blk = blockIdx.x;
    const float* src; u16* dst; long off;
    if (blk < 2048) { src = x; dst = xb; off = (long)blk * 1024; }
    else {
        int w = (blk - 2048) >> 9, bb = (blk - 2048) & 511;
        src = (w == 0 ? wq : w == 1 ? wk : w == 2 ? wv : wp);
        dst = (w == 0 ? wqb : w == 1 ? wkb : w == 2 ? wvb : wpb);
        off = (long)bb * 1024;
    }
    long i = off + threadIdx.x * 4;
    f32x4 v = *(const f32x4*)(src + i);
    u16x4 o;
    o[0] = f2bf(v[0]); o[1] = f2bf(v[1]); o[2] = f2bf(v[2]); o[3] = f2bf(v[3]);
    *(u16x4*)(dst + i) = o;
}

// ---------------- QKV projection GEMM ----------------
// M=8192, N=6144, K=256. BK=128, both-sides chunk-XOR swizzle (R14),
// V epilogue via LDS transpose bounce (R15, -3us). R17's V j-chunk image
// swizzle REVERTED (it tripled bank conflicts: per-lane bank model of the
// 64-lane b128 read was wrong).
// Outputs:
// Q -> [B,H,S,256] linear bf16.
// K -> swizzled tile image: per bh, 32 tiles [32 rows(s)][256 cols(e)],
//      elem (r,c) at u16 idx r*256 + ((c&~7)^((r&7)<<3)) + (c&7).
// V -> PADDED tile image: per bh, 32 tiles [256 rows(e)][40 cols(j)], j<32 valid,
//      elem (e,j) at u16 idx e*40 + j.
__global__ __launch_bounds__(256) void qkv_gemm(
    const u16* __restrict__ xb,
    const u16* __restrict__ Wqb, const u16* __restrict__ Wkb, const u16* __restrict__ Wvb,
    const float* __restrict__ bq, const float* __restrict__ bk, const float* __restrict__ bv,
    u16* __restrict__ Qb, u16* __restrict__ Kimg, u16* __restrict__ Vimg)
{
    __shared__ u16 smem[32768];     // As [0,16384) | Bs [16384,32768); V bounce reuses
    u16* As = smem;                 // [128 m][16 chunks of 8 u16], chunk^row&7
    u16* Bs = smem + 16384;         // [128 n][16 chunks], chunk^row&7
    const int tid  = threadIdx.x;
    const int lane = tid & 63;
    const int li   = lane & 15, lg = lane >> 4;
    const int wave = tid >> 6;
    const int wr   = wave >> 1, wc = wave & 1;
    const int m0   = blockIdx.x * 128;
    const int n0g  = blockIdx.y * 128;
    const int w    = n0g >> 11;            // 0:Q 1:K 2:V
    const int h    = (n0g >> 8) & 7;
    const int e0   = n0g & 255;            // 0 or 128
    const u16* Wsel = (w == 0 ? Wqb : (w == 1 ? Wkb : Wvb)) + h * 65536;

    f32x4 acc[4][4] = {};

    for (int k0 = 0; k0 < 256; k0 += 128) {
        __syncthreads();
        #pragma unroll
        for (int p = 0; p < 8; ++p) {
            const int g = p * 256 + tid, row = g >> 4, cl = g & 15;
            const size_t soff = ((size_t)row) * 256 + k0 + ((cl ^ (row & 7)) * 8);
            GLOAD16(&xb[(size_t)m0 * 256 + soff],   &As[g * 8]);
            GLOAD16(&Wsel[(size_t)e0 * 256 + soff], &Bs[g * 8]);
        }
        __syncthreads();

        #pragma unroll
        for (int kk = 0; kk < 4; ++kk) {
            s16x8 af[4], bf[4];
            #pragma unroll
            for (int mi = 0; mi < 4; ++mi) {
                const int arow = wr * 64 + mi * 16 + li;
                af[mi] = *(const s16x8*)&As[arow * 128 + (((kk * 4 + lg) ^ (arow & 7)) * 8)];
            }
            #pragma unroll
            for (int ni = 0; ni < 4; ++ni) {
                const int brow = wc * 64 + ni * 16 + li;
                bf[ni] = *(const s16x8*)&Bs[brow * 128 + (((kk * 4 + lg) ^ (brow & 7)) * 8)];
            }
            #pragma unroll
            for (int mi = 0; mi < 4; ++mi)
                #pragma unroll
                for (int ni = 0; ni < 4; ++ni)
                    acc[mi][ni] = __builtin_amdgcn_mfma_f32_16x16x32_bf16(af[mi], bf[ni], acc[mi][ni], 0, 0, 0);
        }
    }

    const int b  = m0 >> 10;
    const int s0 = m0 & 1023;
    if (w == 0) {
        const float* bp = bq + 256 * h;
        #pragma unroll
        for (int ni = 0; ni < 4; ++ni) {
            const int e = e0 + wc * 64 + ni * 16 + li;
            const float bias = bp[e];
            u16* obase = Qb + ((size_t)(b * 8 + h)) * 1024 * 256 + e;
            #pragma unroll
            for (int mi = 0; mi < 4; ++mi)
                #pragma unroll
                for (int r = 0; r < 4; ++r) {
                    int s = s0 + wr * 64 + mi * 16 + lg * 4 + r;
                    obase[(size_t)s * 256] = f2bf(acc[mi][ni][r] + bias);
                }
        }
    } else if (w == 1) {
        const float* bp = bk + 256 * h;
        u16* kb = Kimg + ((size_t)(b * 8 + h)) * 262144;
        #pragma unroll
        for (int ni = 0; ni < 4; ++ni) {
            const int e = e0 + wc * 64 + ni * 16 + li;
            const float bias = bp[e];
            #pragma unroll
            for (int mi = 0; mi < 4; ++mi)
                #pragma unroll
                for (int r = 0; r < 4; ++r) {
                    int s = s0 + wr * 64 + mi * 16 + lg * 4 + r;
                    int t = s >> 5, rr = s & 31;
                    size_t idx = (size_t)t * 8192 + rr * 256
                               + (((e & ~7) ^ ((rr & 7) << 3)) | (e & 7));
                    kb[idx] = f2bf(acc[mi][ni][r] + bias);
                }
        }
    } else {
        // V: LDS transpose bounce (R15). Vt[128 e][132 s] u16.
        const float* bp = bv + 256 * h;
        u16* vb = Vimg + ((size_t)(b * 8 + h)) * 327680;
        const int t0 = s0 >> 5;
        u16* Vt = smem;
        __syncthreads();
        #pragma unroll
        for (int ni = 0; ni < 4; ++ni) {
            const int eloc = wc * 64 + ni * 16 + li;
            const float bias = bp[e0 + eloc];
            #pragma unroll
            for (int mi = 0; mi < 4; ++mi) {
                const int sloc = wr * 64 + mi * 16 + lg * 4;
                u16x4 pk;
                #pragma unroll
                for (int r = 0; r < 4; ++r) pk[r] = f2bf(acc[mi][ni][r] + bias);
                *(u16x4*)&Vt[eloc * 132 + sloc] = pk;
            }
        }
        __syncthreads();
        #pragma unroll
        for (int p = 0; p < 8; ++p) {
            const int g    = p * 256 + tid;
            const int eloc = g >> 4;
            const int tt   = (g >> 2) & 3;
            const int ch   = g & 3;
            const int sloc = tt * 32 + ch * 8;
            u16x8 v = *(const u16x8*)&Vt[eloc * 132 + sloc];
            *(u16x8*)&vb[(size_t)(t0 + tt) * 10240 + (size_t)(e0 + eloc) * 40 + ch * 8] = v;
        }
    }
}

// ---------------- flash attention ----------------
// R0/session-best structure (83us) + R18: QK accumulator split into two
// independent chains (even/odd dk). The 2130-cyc MfmaUtil at only ~512 cyc of
// MFMA throughput-need shows QK's 16-deep dependent-accumulate chain exposes
// ~33 cyc latency per MFMA; splitting halves the chain depth (16->8) at the
// cost of 16 VGPRs + 16 v_add_f32 before softmax.
// Everything else identical to the proven R0/R15 state (R17 V-swizzle
// reverted both sides).
__device__ __forceinline__ void softmax_pack(
    f32x16& sacc, float& m_run, float& l_run, f32x16* oacc,
    int hi, s16x8& paA, s16x8& paB)
{
    const float C = 0.09016844f;       // log2(e)/sqrt(256)
    const float THR = 16.0f;           // defer-max threshold (raw S units)
    float pm = -1e30f;
    #pragma unroll
    for (int r = 0; r < 16; ++r) pm = fmaxf(pm, sacc[r]);
    pm = fmaxf(pm, __shfl_xor(pm, 32));
    if (!__all(pm - m_run <= THR)) {   // rare
        const float mnew = fmaxf(m_run, pm);
        const float corr = __builtin_amdgcn_exp2f((m_run - mnew) * C);
        l_run *= corr;
        #pragma unroll
        for (int r = 0; r < 16; ++r) {
            float rc = __shfl(corr, (r & 3) + 8 * (r >> 2) + 4 * hi);
            #pragma unroll
            for (int et = 0; et < 8; ++et) oacc[et][r] *= rc;
        }
        m_run = mnew;
    }
    float psum = 0.f;
    #pragma unroll
    for (int r = 0; r < 16; ++r) {
        float p = __builtin_amdgcn_exp2f((sacc[r] - m_run) * C);
        psum += p;
        sacc[r] = p;
    }
    psum += __shfl_xor(psum, 32);
    l_run += psum;
    unsigned dwA[4], dwB[4];
    #pragma unroll
    for (int c = 0; c < 4; ++c) {
        asm("v_cvt_pk_bf16_f32 %0, %1, %2" : "=v"(dwA[c]) : "v"(sacc[4*c]),   "v"(sacc[4*c+1]));
        asm("v_cvt_pk_bf16_f32 %0, %1, %2" : "=v"(dwB[c]) : "v"(sacc[4*c+2]), "v"(sacc[4*c+3]));
    }
    {
        unsigned a0 = dwA[0], a1 = dwA[1], b0 = dwB[0], b1 = dwB[1];
        asm("v_permlane32_swap_b32 %0, %1" : "+v"(a0), "+v"(a1));
        asm("v_permlane32_swap_b32 %0, %1" : "+v"(b0), "+v"(b1));
        union { unsigned u[4]; s16x8 v; } pk;
        pk.u[0] = a0; pk.u[1] = b0; pk.u[2] = a1; pk.u[3] = b1;
        paA = pk.v;
    }
    {
        unsigned a0 = dwA[2], a1 = dwA[3], b0 = dwB[2], b1 = dwB[3];
        asm("v_permlane32_swap_b32 %0, %1" : "+v"(a0), "+v"(a1));
        asm("v_permlane32_swap_b32 %0, %1" : "+v"(b0), "+v"(b1));
        union { unsigned u[4]; s16x8 v; } pk;
        pk.u[0] = a0; pk.u[1] = b0; pk.u[2] = a1; pk.u[3] = b1;
        paB = pk.v;
    }
}

__global__ __launch_bounds__(512, 2) void attn(
    const u16* __restrict__ Qb, const u16* __restrict__ Kimg,
    const u16* __restrict__ Vimg, u16* __restrict__ Ob)
{
    __shared__ u16 kbuf[3][8192];      // [32 j][256 d] swizzled, 16KB each
    __shared__ u16 vbuf[3][10240];     // [256 e][40 j] padded, 20KB each
    const int tid  = threadIdx.x;
    const int lane = tid & 63;
    const int wave = tid >> 6;
    const int col  = lane & 31;        // q-row for S, e-col for O
    const int hi   = lane >> 5;
    const int hi8  = hi * 8;
    const int ksw  = (lane & 7) << 3;  // K-read XOR swizzle
    // XCD swizzle: 256 blocks, 32 per XCD -> 8 distinct (b,h) per XCD
    const int bid  = ((blockIdx.x & 7) << 5) | (blockIdx.x >> 3);
    const int bh   = bid >> 2;
    const int qblk = bid & 3;
    const int q0   = qblk * 256 + wave * 32;   // wave's 32 q-rows

    const u16* qp = Qb + ((size_t)bh * 1024 + q0) * 256;
    const u16* kg = Kimg + (size_t)bh * 262144;
    const u16* vg = Vimg + (size_t)bh * 327680;

    // capture-safe role-split stage: waves 0-3 -> K (4 loads), 4-7 -> V (5 loads)
    #define STAGE(sl, t)                                                          \
        {                                                                         \
            const int sl_ = (sl);                                                 \
            const int t_  = (t);                                                  \
            if (tid < 256) {                                                      \
                const size_t kb_ = (size_t)t_ * 8192 + tid * 8;                   \
                _Pragma("unroll")                                                 \
                for (int c_ = 0; c_ < 4; ++c_)                                    \
                    GLOAD16(&kg[kb_ + c_ * 2048], &kbuf[sl_][c_ * 2048 + tid * 8]); \
            } else {                                                              \
                const int    vt_ = tid - 256;                                     \
                const size_t vb_ = (size_t)t_ * 10240 + vt_ * 8;                  \
                _Pragma("unroll")                                                 \
                for (int c_ = 0; c_ < 5; ++c_)                                    \
                    GLOAD16(&vg[vb_ + c_ * 2048], &vbuf[sl_][c_ * 2048 + vt_ * 8]); \
            }                                                                     \
        }

    // Q B-frags first (their vmcnt retires before the batches we count against)
    s16x8 qf[16];
    #pragma unroll
    for (int dk = 0; dk < 16; ++dk)
        qf[dk] = *(const s16x8*)&qp[(size_t)col * 256 + dk * 16 + hi8];

    // prologue: 3 batches in flight
    STAGE(0, 0);
    STAGE(1, 1);
    STAGE(2, 2);

    f32x16 oacc[8] = {};               // O[q=crow(r,hi)][e=et*32+col]
    float m_run = -1e30f, l_run = 0.f;
    f32x16 sacc;
    s16x8 paA, paB;

    for (int i = 0; i < 32; ++i) {
        // counted wait: allow 2 newest batches in flight -> batch i resident
        if (tid < 256) { asm volatile("s_waitcnt vmcnt(8)"  ::: "memory"); }
        else           { asm volatile("s_waitcnt vmcnt(10)" ::: "memory"); }
        __builtin_amdgcn_s_barrier();              // barrier-A: whole tile i visible
        asm volatile("" ::: "memory");
        const int slot = i % 3;
        const u16* kt = kbuf[slot];
        const u16* vt = vbuf[slot];

        __builtin_amdgcn_s_setprio(1);
        {   // QK: S[j=crow(r,hi)][q=col]; two independent chains (R18)
            f32x16 sa = (f32x16){}, sb = (f32x16){};
            const int rb_ = col * 256;
            #pragma unroll
            for (int dk_ = 0; dk_ < 16; dk_ += 2) {
                s16x8 kf0 = *(const s16x8*)&kt[rb_ + ((dk_ * 16 + hi8) ^ ksw)];
                s16x8 kf1 = *(const s16x8*)&kt[rb_ + (((dk_ + 1) * 16 + hi8) ^ ksw)];
                sa = __builtin_amdgcn_mfma_f32_32x32x16_bf16(kf0, qf[dk_],     sa, 0, 0, 0);
                sb = __builtin_amdgcn_mfma_f32_32x32x16_bf16(kf1, qf[dk_ + 1], sb, 0, 0, 0);
            }
            #pragma unroll
            for (int r = 0; r < 16; ++r) sacc[r] = sa[r] + sb[r];
        }
        __builtin_amdgcn_s_setprio(0);

        softmax_pack(sacc, m_run, l_run, oacc, hi, paA, paB);

        __builtin_amdgcn_s_setprio(1);
        {   // PV
            #pragma unroll
            for (int et_ = 0; et_ < 8; ++et_) {
                s16x8 vf = *(const s16x8*)&vt[(et_ * 32 + col) * 40 + hi8];
                oacc[et_] = __builtin_amdgcn_mfma_f32_32x32x16_bf16(paA, vf, oacc[et_], 0, 0, 0);
            }
            #pragma unroll
            for (int et_ = 0; et_ < 8; ++et_) {
                s16x8 vf = *(const s16x8*)&vt[(et_ * 32 + col) * 40 + 16 + hi8];
                oacc[et_] = __builtin_amdgcn_mfma_f32_32x32x16_bf16(paB, vf, oacc[et_], 0, 0, 0);
            }
        }
        __builtin_amdgcn_s_setprio(0);

        asm volatile("" ::: "memory");
        __builtin_amdgcn_s_barrier();              // barrier-B: slot reads done
        asm volatile("" ::: "memory");
        const int nt = (i + 3 < 32) ? (i + 3) : 31;   // clamp keeps count invariant
        STAGE(slot, nt);                           // slot (i+3)%3 == i%3, just freed
    }
    #undef STAGE

    // normalize + store: Ob [B,S,H*256]
    const float linv = 1.0f / l_run;
    const int b = bh >> 3, h = bh & 7;
    u16* op = Ob + ((size_t)b * 1024) * 2048 + h * 256;
    #pragma unroll
    for (int r = 0; r < 16; ++r) {
        const int crow = (r & 3) + 8 * (r >> 2) + 4 * hi;
        float lr = __shfl(linv, crow);
        const size_t row = q0 + crow;
        #pragma unroll
        for (int et = 0; et < 8; ++et)
            op[row * 2048 + et * 32 + col] = f2bf(oacc[et][r] * lr);
    }
}

// ---------------- output projection ----------------
// out[m, n] = sum_k Ob[m, k] * Wp[n, k]; M=8192, N=256, K=2048; fp32 out.
// R13 (validated, -11us): BK=128, 16 iters x 16 MFMAs/wave/iter, 40KB LDS,
// both-sides chunk-XOR swizzle (cl ^ (row&7)).
__global__ __launch_bounds__(256) void out_gemm(
    const u16* __restrict__ Ob, const u16* __restrict__ Wpb, float* __restrict__ out)
{
    __shared__ u16 As[32 * 128];    // [32 m][16 chunks of 8 u16], chunk^row&7
    __shared__ u16 Bs[128 * 128];   // [128 n][16 chunks], chunk^row&7
    const int tid  = threadIdx.x;
    const int lane = tid & 63;
    const int li   = lane & 15, lg = lane >> 4;
    const int wave = tid >> 6;
    const int wr   = wave >> 1, wc = wave & 1;   // wave tile 16x64
    const int m0   = blockIdx.x * 32;
    const int n0   = blockIdx.y * 128;

    f32x4 acc[4] = {};

    for (int k0 = 0; k0 < 2048; k0 += 128) {
        __syncthreads();
        #pragma unroll
        for (int p = 0; p < 2; ++p) {
            const int g = p * 256 + tid, row = g >> 4, cl = g & 15;
            GLOAD16(&Ob[(size_t)(m0 + row) * 2048 + k0 + ((cl ^ (row & 7)) * 8)],
                    &As[g * 8]);
        }
        #pragma unroll
        for (int p = 0; p < 8; ++p) {
            const int g = p * 256 + tid, row = g >> 4, cl = g & 15;
            GLOAD16(&Wpb[(size_t)(n0 + row) * 2048 + k0 + ((cl ^ (row & 7)) * 8)],
                    &Bs[g * 8]);
        }
        __syncthreads();

        const int arow = wr * 16 + li;
        s16x8 af[4];
        #pragma unroll
        for (int kk = 0; kk < 4; ++kk)
            af[kk] = *(const s16x8*)&As[arow * 128 + (((kk * 4 + lg) ^ (arow & 7)) * 8)];
        #pragma unroll
        for (int ni = 0; ni < 4; ++ni) {
            const int brow = wc * 64 + ni * 16 + li;
            #pragma unroll
            for (int kk = 0; kk < 4; ++kk) {
                s16x8 bf = *(const s16x8*)&Bs[brow * 128 + (((kk * 4 + lg) ^ (brow & 7)) * 8)];
                acc[ni] = __builtin_amdgcn_mfma_f32_16x16x32_bf16(af[kk], bf, acc[ni], 0, 0, 0);
            }
        }
    }

    #pragma unroll
    for (int ni = 0; ni < 4; ++ni) {
        int n = n0 + wc * 64 + ni * 16 + li;
        #pragma unroll
        for (int r = 0; r < 4; ++r) {
            int m = m0 + wr * 16 + lg * 4 + r;
            out[(size_t)m * 256 + n] = acc[ni][r];
        }
    }
}

extern "C" void kernel_launch(void* const* d_in, const int* in_sizes, int n_in,
                              void* d_out, int out_size, void* d_ws, size_t ws_size,
                              hipStream_t stream) {
    const float* x  = (const float*)d_in[0];
    const float* Wq = (const float*)d_in[1];
    const float* Wk = (const float*)d_in[2];
    const float* Wv = (const float*)d_in[3];
    const float* bq = (const float*)d_in[4];
    const float* bk = (const float*)d_in[5];
    const float* bv = (const float*)d_in[6];
    const float* Wp = (const float*)d_in[7];
    float* out = (float*)d_out;

    u16* xb   = (u16*)d_ws;               // 2,097,152
    u16* Wqb  = xb   + (1u << 21);        // 524,288 each
    u16* Wkb  = Wqb  + (1u << 19);
    u16* Wvb  = Wkb  + (1u << 19);
    u16* Wpb  = Wvb  + (1u << 19);
    u16* Qb   = Wpb  + (1u << 19);        // 16,777,216
    u16* Kimg = Qb   + (1u << 24);        // 16,777,216
    u16* Vimg = Kimg + (1u << 24);        // 20,971,520 (padded V)
    u16* Ob   = Vimg + 20971520u;         // 16,777,216

    castall<<<4096, 256, 0, stream>>>(x, Wq, Wk, Wv, Wp, xb, Wqb, Wkb, Wvb, Wpb);
    qkv_gemm<<<dim3(64, 48), 256, 0, stream>>>(xb, Wqb, Wkb, Wvb, bq, bk, bv, Qb, Kimg, Vimg);
    attn<<<256, 512, 0, stream>>>(Qb, Kimg, Vimg, Ob);
    out_gemm<<<dim3(256, 2), 256, 0, stream>>>(Ob, Wpb, out);
}

// Round 11
// 153.270 us; speedup vs baseline: 1.0731x; 1.0731x over previous
//
#include <hip/hip_runtime.h>

typedef unsigned short u16;
typedef __attribute__((ext_vector_type(4)))  float f32x4;
typedef __attribute__((ext_vector_type(16))) float f32x16;
typedef __attribute__((ext_vector_type(8)))  short s16x8;   // 8 bf16 MFMA fragment
typedef __attribute__((ext_vector_type(4)))  unsigned short u16x4;
typedef __attribute__((ext_vector_type(8)))  unsigned short u16x8;

typedef const __attribute__((address_space(1))) void* gp1;
typedef __attribute__((address_space(3))) void* lp3;
#define GLOAD16(g, l) __builtin_amdgcn_global_load_lds((gp1)(g), (lp3)(l), 16, 0, 0)

__device__ __forceinline__ u16 f2bf(float f) {
    union { float f; unsigned u; } c; c.f = f;
    unsigned r = c.u + 0x7fffu + ((c.u >> 16) & 1u);   // RNE
    return (u16)(r >> 16);
}

// ---------------- fp32 -> bf16 cast (all 5 arrays, one launch) ----------------
__global__ void castall(const float* __restrict__ x,  const float* __restrict__ wq,
                        const float* __restrict__ wk, const float* __restrict__ wv,
                        const float* __restrict__ wp,
                        u16* __restrict__ xb,  u16* __restrict__ wqb, u16* __restrict__ wkb,
                        u16* __restrict__ wvb, u16* __restrict__ wpb) {
    int blk = blockIdx.x;
    const float* src; u16* dst; long off;
    if (blk < 2048) { src = x; dst = xb; off = (long)blk * 1024; }
    else {
        int w = (blk - 2048) >> 9, bb = (blk - 2048) & 511;
        src = (w == 0 ? wq : w == 1 ? wk : w == 2 ? wv : wp);
        dst = (w == 0 ? wqb : w == 1 ? wkb : w == 2 ? wvb : wpb);
        off = (long)bb * 1024;
    }
    long i = off + threadIdx.x * 4;
    f32x4 v = *(const f32x4*)(src + i);
    u16x4 o;
    o[0] = f2bf(v[0]); o[1] = f2bf(v[1]); o[2] = f2bf(v[2]); o[3] = f2bf(v[3]);
    *(u16x4*)(dst + i) = o;
}

// ---------------- QKV projection GEMM ----------------
// M=8192, N=6144, K=256. BK=128, both-sides chunk-XOR swizzle (R14),
// V epilogue via LDS transpose bounce (R15, -3us).
// Outputs:
// Q -> [B,H,S,256] linear bf16.
// K -> swizzled tile image: per bh, 32 tiles [32 rows(s)][256 cols(e)],
//      elem (r,c) at u16 idx r*256 + ((c&~7)^((r&7)<<3)) + (c&7).
// V -> PADDED tile image: per bh, 32 tiles [256 rows(e)][40 cols(j)], j<32 valid,
//      elem (e,j) at u16 idx e*40 + j.
__global__ __launch_bounds__(256) void qkv_gemm(
    const u16* __restrict__ xb,
    const u16* __restrict__ Wqb, const u16* __restrict__ Wkb, const u16* __restrict__ Wvb,
    const float* __restrict__ bq, const float* __restrict__ bk, const float* __restrict__ bv,
    u16* __restrict__ Qb, u16* __restrict__ Kimg, u16* __restrict__ Vimg)
{
    __shared__ u16 smem[32768];     // As [0,16384) | Bs [16384,32768); V bounce reuses
    u16* As = smem;                 // [128 m][16 chunks of 8 u16], chunk^row&7
    u16* Bs = smem + 16384;         // [128 n][16 chunks], chunk^row&7
    const int tid  = threadIdx.x;
    const int lane = tid & 63;
    const int li   = lane & 15, lg = lane >> 4;
    const int wave = tid >> 6;
    const int wr   = wave >> 1, wc = wave & 1;
    const int m0   = blockIdx.x * 128;
    const int n0g  = blockIdx.y * 128;
    const int w    = n0g >> 11;            // 0:Q 1:K 2:V
    const int h    = (n0g >> 8) & 7;
    const int e0   = n0g & 255;            // 0 or 128
    const u16* Wsel = (w == 0 ? Wqb : (w == 1 ? Wkb : Wvb)) + h * 65536;

    f32x4 acc[4][4] = {};

    for (int k0 = 0; k0 < 256; k0 += 128) {
        __syncthreads();
        #pragma unroll
        for (int p = 0; p < 8; ++p) {
            const int g = p * 256 + tid, row = g >> 4, cl = g & 15;
            const size_t soff = ((size_t)row) * 256 + k0 + ((cl ^ (row & 7)) * 8);
            GLOAD16(&xb[(size_t)m0 * 256 + soff],   &As[g * 8]);
            GLOAD16(&Wsel[(size_t)e0 * 256 + soff], &Bs[g * 8]);
        }
        __syncthreads();

        #pragma unroll
        for (int kk = 0; kk < 4; ++kk) {
            s16x8 af[4], bf[4];
            #pragma unroll
            for (int mi = 0; mi < 4; ++mi) {
                const int arow = wr * 64 + mi * 16 + li;
                af[mi] = *(const s16x8*)&As[arow * 128 + (((kk * 4 + lg) ^ (arow & 7)) * 8)];
            }
            #pragma unroll
            for (int ni = 0; ni < 4; ++ni) {
                const int brow = wc * 64 + ni * 16 + li;
                bf[ni] = *(const s16x8*)&Bs[brow * 128 + (((kk * 4 + lg) ^ (brow & 7)) * 8)];
            }
            #pragma unroll
            for (int mi = 0; mi < 4; ++mi)
                #pragma unroll
                for (int ni = 0; ni < 4; ++ni)
                    acc[mi][ni] = __builtin_amdgcn_mfma_f32_16x16x32_bf16(af[mi], bf[ni], acc[mi][ni], 0, 0, 0);
        }
    }

    const int b  = m0 >> 10;
    const int s0 = m0 & 1023;
    if (w == 0) {
        const float* bp = bq + 256 * h;
        #pragma unroll
        for (int ni = 0; ni < 4; ++ni) {
            const int e = e0 + wc * 64 + ni * 16 + li;
            const float bias = bp[e];
            u16* obase = Qb + ((size_t)(b * 8 + h)) * 1024 * 256 + e;
            #pragma unroll
            for (int mi = 0; mi < 4; ++mi)
                #pragma unroll
                for (int r = 0; r < 4; ++r) {
                    int s = s0 + wr * 64 + mi * 16 + lg * 4 + r;
                    obase[(size_t)s * 256] = f2bf(acc[mi][ni][r] + bias);
                }
        }
    } else if (w == 1) {
        const float* bp = bk + 256 * h;
        u16* kb = Kimg + ((size_t)(b * 8 + h)) * 262144;
        #pragma unroll
        for (int ni = 0; ni < 4; ++ni) {
            const int e = e0 + wc * 64 + ni * 16 + li;
            const float bias = bp[e];
            #pragma unroll
            for (int mi = 0; mi < 4; ++mi)
                #pragma unroll
                for (int r = 0; r < 4; ++r) {
                    int s = s0 + wr * 64 + mi * 16 + lg * 4 + r;
                    int t = s >> 5, rr = s & 31;
                    size_t idx = (size_t)t * 8192 + rr * 256
                               + (((e & ~7) ^ ((rr & 7) << 3)) | (e & 7));
                    kb[idx] = f2bf(acc[mi][ni][r] + bias);
                }
        }
    } else {
        // V: LDS transpose bounce (R15). Vt[128 e][132 s] u16.
        const float* bp = bv + 256 * h;
        u16* vb = Vimg + ((size_t)(b * 8 + h)) * 327680;
        const int t0 = s0 >> 5;
        u16* Vt = smem;
        __syncthreads();
        #pragma unroll
        for (int ni = 0; ni < 4; ++ni) {
            const int eloc = wc * 64 + ni * 16 + li;
            const float bias = bp[e0 + eloc];
            #pragma unroll
            for (int mi = 0; mi < 4; ++mi) {
                const int sloc = wr * 64 + mi * 16 + lg * 4;
                u16x4 pk;
                #pragma unroll
                for (int r = 0; r < 4; ++r) pk[r] = f2bf(acc[mi][ni][r] + bias);
                *(u16x4*)&Vt[eloc * 132 + sloc] = pk;
            }
        }
        __syncthreads();
        #pragma unroll
        for (int p = 0; p < 8; ++p) {
            const int g    = p * 256 + tid;
            const int eloc = g >> 4;
            const int tt   = (g >> 2) & 3;
            const int ch   = g & 3;
            const int sloc = tt * 32 + ch * 8;
            u16x8 v = *(const u16x8*)&Vt[eloc * 132 + sloc];
            *(u16x8*)&vb[(size_t)(t0 + tt) * 10240 + (size_t)(e0 + eloc) * 40 + ch * 8] = v;
        }
    }
}

// ---------------- flash attention ----------------
// EXACT R0/session-best structure (83us, proven across many runs). Frozen:
// six perturbations (R9 PV-lag, R10 2-block, R12 SM-first, R16 parity split,
// R17 V-swizzle, R18 chain split) were all neutral-or-worse — this schedule
// is a sharply-tuned latency-bound local optimum; escaping it needs a full
// co-designed rewrite, not increments.
// 256 blocks = 64 (b,h) * 4 q-blocks; 8 waves (512 thr), 1 block/CU (108KB LDS).
// TRIPLE-buffered K and V; role-split staging (waves 0-3 K: 4 loads/iter,
// waves 4-7 V: 5 loads/iter); counted vmcnt(8)/vmcnt(10) at top of iter;
// raw s_barrier. Ledger: iter i reads slot i%3 between barrier-A and
// barrier-B; stage after barrier-B targets slot (i+3)%3 == i%3 (just freed);
// clamped tail re-stage keeps the vmcnt count invariant.
__device__ __forceinline__ void softmax_pack(
    f32x16& sacc, float& m_run, float& l_run, f32x16* oacc,
    int hi, s16x8& paA, s16x8& paB)
{
    const float C = 0.09016844f;       // log2(e)/sqrt(256)
    const float THR = 16.0f;           // defer-max threshold (raw S units)
    float pm = -1e30f;
    #pragma unroll
    for (int r = 0; r < 16; ++r) pm = fmaxf(pm, sacc[r]);
    pm = fmaxf(pm, __shfl_xor(pm, 32));
    if (!__all(pm - m_run <= THR)) {   // rare
        const float mnew = fmaxf(m_run, pm);
        const float corr = __builtin_amdgcn_exp2f((m_run - mnew) * C);
        l_run *= corr;
        #pragma unroll
        for (int r = 0; r < 16; ++r) {
            float rc = __shfl(corr, (r & 3) + 8 * (r >> 2) + 4 * hi);
            #pragma unroll
            for (int et = 0; et < 8; ++et) oacc[et][r] *= rc;
        }
        m_run = mnew;
    }
    float psum = 0.f;
    #pragma unroll
    for (int r = 0; r < 16; ++r) {
        float p = __builtin_amdgcn_exp2f((sacc[r] - m_run) * C);
        psum += p;
        sacc[r] = p;
    }
    psum += __shfl_xor(psum, 32);
    l_run += psum;
    unsigned dwA[4], dwB[4];
    #pragma unroll
    for (int c = 0; c < 4; ++c) {
        asm("v_cvt_pk_bf16_f32 %0, %1, %2" : "=v"(dwA[c]) : "v"(sacc[4*c]),   "v"(sacc[4*c+1]));
        asm("v_cvt_pk_bf16_f32 %0, %1, %2" : "=v"(dwB[c]) : "v"(sacc[4*c+2]), "v"(sacc[4*c+3]));
    }
    {
        unsigned a0 = dwA[0], a1 = dwA[1], b0 = dwB[0], b1 = dwB[1];
        asm("v_permlane32_swap_b32 %0, %1" : "+v"(a0), "+v"(a1));
        asm("v_permlane32_swap_b32 %0, %1" : "+v"(b0), "+v"(b1));
        union { unsigned u[4]; s16x8 v; } pk;
        pk.u[0] = a0; pk.u[1] = b0; pk.u[2] = a1; pk.u[3] = b1;
        paA = pk.v;
    }
    {
        unsigned a0 = dwA[2], a1 = dwA[3], b0 = dwB[2], b1 = dwB[3];
        asm("v_permlane32_swap_b32 %0, %1" : "+v"(a0), "+v"(a1));
        asm("v_permlane32_swap_b32 %0, %1" : "+v"(b0), "+v"(b1));
        union { unsigned u[4]; s16x8 v; } pk;
        pk.u[0] = a0; pk.u[1] = b0; pk.u[2] = a1; pk.u[3] = b1;
        paB = pk.v;
    }
}

__global__ __launch_bounds__(512, 2) void attn(
    const u16* __restrict__ Qb, const u16* __restrict__ Kimg,
    const u16* __restrict__ Vimg, u16* __restrict__ Ob)
{
    __shared__ u16 kbuf[3][8192];      // [32 j][256 d] swizzled, 16KB each
    __shared__ u16 vbuf[3][10240];     // [256 e][40 j] padded, 20KB each
    const int tid  = threadIdx.x;
    const int lane = tid & 63;
    const int wave = tid >> 6;
    const int col  = lane & 31;        // q-row for S, e-col for O
    const int hi   = lane >> 5;
    const int hi8  = hi * 8;
    const int ksw  = (lane & 7) << 3;  // K-read XOR swizzle
    // XCD swizzle: 256 blocks, 32 per XCD -> 8 distinct (b,h) per XCD
    const int bid  = ((blockIdx.x & 7) << 5) | (blockIdx.x >> 3);
    const int bh   = bid >> 2;
    const int qblk = bid & 3;
    const int q0   = qblk * 256 + wave * 32;   // wave's 32 q-rows

    const u16* qp = Qb + ((size_t)bh * 1024 + q0) * 256;
    const u16* kg = Kimg + (size_t)bh * 262144;
    const u16* vg = Vimg + (size_t)bh * 327680;

    // capture-safe role-split stage: waves 0-3 -> K (4 loads), 4-7 -> V (5 loads)
    #define STAGE(sl, t)                                                          \
        {                                                                         \
            const int sl_ = (sl);                                                 \
            const int t_  = (t);                                                  \
            if (tid < 256) {                                                      \
                const size_t kb_ = (size_t)t_ * 8192 + tid * 8;                   \
                _Pragma("unroll")                                                 \
                for (int c_ = 0; c_ < 4; ++c_)                                    \
                    GLOAD16(&kg[kb_ + c_ * 2048], &kbuf[sl_][c_ * 2048 + tid * 8]); \
            } else {                                                              \
                const int    vt_ = tid - 256;                                     \
                const size_t vb_ = (size_t)t_ * 10240 + vt_ * 8;                  \
                _Pragma("unroll")                                                 \
                for (int c_ = 0; c_ < 5; ++c_)                                    \
                    GLOAD16(&vg[vb_ + c_ * 2048], &vbuf[sl_][c_ * 2048 + vt_ * 8]); \
            }                                                                     \
        }

    // Q B-frags first (their vmcnt retires before the batches we count against)
    s16x8 qf[16];
    #pragma unroll
    for (int dk = 0; dk < 16; ++dk)
        qf[dk] = *(const s16x8*)&qp[(size_t)col * 256 + dk * 16 + hi8];

    // prologue: 3 batches in flight
    STAGE(0, 0);
    STAGE(1, 1);
    STAGE(2, 2);

    f32x16 oacc[8] = {};               // O[q=crow(r,hi)][e=et*32+col]
    float m_run = -1e30f, l_run = 0.f;
    f32x16 sacc;
    s16x8 paA, paB;

    for (int i = 0; i < 32; ++i) {
        // counted wait: allow 2 newest batches in flight -> batch i resident
        if (tid < 256) { asm volatile("s_waitcnt vmcnt(8)"  ::: "memory"); }
        else           { asm volatile("s_waitcnt vmcnt(10)" ::: "memory"); }
        __builtin_amdgcn_s_barrier();              // barrier-A: whole tile i visible
        asm volatile("" ::: "memory");
        const int slot = i % 3;
        const u16* kt = kbuf[slot];
        const u16* vt = vbuf[slot];

        __builtin_amdgcn_s_setprio(1);
        {   // QK: S[j=crow(r,hi)][q=col]
            sacc = (f32x16){};
            const int rb_ = col * 256;
            #pragma unroll
            for (int dk_ = 0; dk_ < 16; ++dk_) {
                s16x8 kf = *(const s16x8*)&kt[rb_ + ((dk_ * 16 + hi8) ^ ksw)];
                sacc = __builtin_amdgcn_mfma_f32_32x32x16_bf16(kf, qf[dk_], sacc, 0, 0, 0);
            }
        }
        __builtin_amdgcn_s_setprio(0);

        softmax_pack(sacc, m_run, l_run, oacc, hi, paA, paB);

        __builtin_amdgcn_s_setprio(1);
        {   // PV
            #pragma unroll
            for (int et_ = 0; et_ < 8; ++et_) {
                s16x8 vf = *(const s16x8*)&vt[(et_ * 32 + col) * 40 + hi8];
                oacc[et_] = __builtin_amdgcn_mfma_f32_32x32x16_bf16(paA, vf, oacc[et_], 0, 0, 0);
            }
            #pragma unroll
            for (int et_ = 0; et_ < 8; ++et_) {
                s16x8 vf = *(const s16x8*)&vt[(et_ * 32 + col) * 40 + 16 + hi8];
                oacc[et_] = __builtin_amdgcn_mfma_f32_32x32x16_bf16(paB, vf, oacc[et_], 0, 0, 0);
            }
        }
        __builtin_amdgcn_s_setprio(0);

        asm volatile("" ::: "memory");
        __builtin_amdgcn_s_barrier();              // barrier-B: slot reads done
        asm volatile("" ::: "memory");
        const int nt = (i + 3 < 32) ? (i + 3) : 31;   // clamp keeps count invariant
        STAGE(slot, nt);                           // slot (i+3)%3 == i%3, just freed
    }
    #undef STAGE

    // normalize + store: Ob [B,S,H*256]
    const float linv = 1.0f / l_run;
    const int b = bh >> 3, h = bh & 7;
    u16* op = Ob + ((size_t)b * 1024) * 2048 + h * 256;
    #pragma unroll
    for (int r = 0; r < 16; ++r) {
        const int crow = (r & 3) + 8 * (r >> 2) + 4 * hi;
        float lr = __shfl(linv, crow);
        const size_t row = q0 + crow;
        #pragma unroll
        for (int et = 0; et < 8; ++et)
            op[row * 2048 + et * 32 + col] = f2bf(oacc[et][r] * lr);
    }
}

// ---------------- output projection ----------------
// out[m, n] = sum_k Ob[m, k] * Wp[n, k]; M=8192, N=256, K=2048; fp32 out.
// R19: BM 32 -> 64, 512 threads (8 waves, same 16x64 wave tile). Staging
// analysis: at BM=32, Wpb was re-staged by 256 m-blocks (256MB B-traffic,
// staging-bound: L2 floor ~9.5us vs 3.6us MFMA). BM=64 halves B-staging
// (total 320->192MB). Grid (128,2)=256 blocks, LDS 48KB. Swizzle template
// unchanged (cl ^ (row&7), validated in R13/R14).
__global__ __launch_bounds__(512) void out_gemm(
    const u16* __restrict__ Ob, const u16* __restrict__ Wpb, float* __restrict__ out)
{
    __shared__ u16 As[64 * 128];    // [64 m][16 chunks of 8 u16], chunk^row&7
    __shared__ u16 Bs[128 * 128];   // [128 n][16 chunks], chunk^row&7
    const int tid  = threadIdx.x;       // 0..511
    const int lane = tid & 63;
    const int li   = lane & 15, lg = lane >> 4;
    const int wave = tid >> 6;          // 0..7
    const int wr   = wave >> 1;         // 0..3 (m, 16 rows each)
    const int wc   = wave & 1;          // 0..1 (n, 64 cols each)
    const int m0   = blockIdx.x * 64;
    const int n0   = blockIdx.y * 128;

    f32x4 acc[4] = {};

    for (int k0 = 0; k0 < 2048; k0 += 128) {
        __syncthreads();
        // stage A: 64 rows x 16 chunks = 1024 chunks, 2 passes of 512
        #pragma unroll
        for (int p = 0; p < 2; ++p) {
            const int g = p * 512 + tid, row = g >> 4, cl = g & 15;
            GLOAD16(&Ob[(size_t)(m0 + row) * 2048 + k0 + ((cl ^ (row & 7)) * 8)],
                    &As[g * 8]);
        }
        // stage B: 2048 chunks, 4 passes of 512
        #pragma unroll
        for (int p = 0; p < 4; ++p) {
            const int g = p * 512 + tid, row = g >> 4, cl = g & 15;
            GLOAD16(&Wpb[(size_t)(n0 + row) * 2048 + k0 + ((cl ^ (row & 7)) * 8)],
                    &Bs[g * 8]);
        }
        __syncthreads();

        const int arow = wr * 16 + li;
        s16x8 af[4];
        #pragma unroll
        for (int kk = 0; kk < 4; ++kk)
            af[kk] = *(const s16x8*)&As[arow * 128 + (((kk * 4 + lg) ^ (arow & 7)) * 8)];
        #pragma unroll
        for (int ni = 0; ni < 4; ++ni) {
            const int brow = wc * 64 + ni * 16 + li;
            #pragma unroll
            for (int kk = 0; kk < 4; ++kk) {
                s16x8 bf = *(const s16x8*)&Bs[brow * 128 + (((kk * 4 + lg) ^ (brow & 7)) * 8)];
                acc[ni] = __builtin_amdgcn_mfma_f32_16x16x32_bf16(af[kk], bf, acc[ni], 0, 0, 0);
            }
        }
    }

    #pragma unroll
    for (int ni = 0; ni < 4; ++ni) {
        int n = n0 + wc * 64 + ni * 16 + li;
        #pragma unroll
        for (int r = 0; r < 4; ++r) {
            int m = m0 + wr * 16 + lg * 4 + r;
            out[(size_t)m * 256 + n] = acc[ni][r];
        }
    }
}

extern "C" void kernel_launch(void* const* d_in, const int* in_sizes, int n_in,
                              void* d_out, int out_size, void* d_ws, size_t ws_size,
                              hipStream_t stream) {
    const float* x  = (const float*)d_in[0];
    const float* Wq = (const float*)d_in[1];
    const float* Wk = (const float*)d_in[2];
    const float* Wv = (const float*)d_in[3];
    const float* bq = (const float*)d_in[4];
    const float* bk = (const float*)d_in[5];
    const float* bv = (const float*)d_in[6];
    const float* Wp = (const float*)d_in[7];
    float* out = (float*)d_out;

    u16* xb   = (u16*)d_ws;               // 2,097,152
    u16* Wqb  = xb   + (1u << 21);        // 524,288 each
    u16* Wkb  = Wqb  + (1u << 19);
    u16* Wvb  = Wkb  + (1u << 19);
    u16* Wpb  = Wvb  + (1u << 19);
    u16* Qb   = Wpb  + (1u << 19);        // 16,777,216
    u16* Kimg = Qb   + (1u << 24);        // 16,777,216
    u16* Vimg = Kimg + (1u << 24);        // 20,971,520 (padded V)
    u16* Ob   = Vimg + 20971520u;         // 16,777,216

    castall<<<4096, 256, 0, stream>>>(x, Wq, Wk, Wv, Wp, xb, Wqb, Wkb, Wvb, Wpb);
    qkv_gemm<<<dim3(64, 48), 256, 0, stream>>>(xb, Wqb, Wkb, Wvb, bq, bk, bv, Qb, Kimg, Vimg);
    attn<<<256, 512, 0, stream>>>(Qb, Kimg, Vimg, Ob);
    out_gemm<<<dim3(128, 2), 512, 0, stream>>>(Ob, Wpb, out);
}

// Round 12
// 151.223 us; speedup vs baseline: 1.0876x; 1.0135x over previous
//
#include <hip/hip_runtime.h>

typedef unsigned short u16;
typedef __attribute__((ext_vector_type(4)))  float f32x4;
typedef __attribute__((ext_vector_type(16))) float f32x16;
typedef __attribute__((ext_vector_type(8)))  short s16x8;   // 8 bf16 MFMA fragment
typedef __attribute__((ext_vector_type(4)))  unsigned short u16x4;
typedef __attribute__((ext_vector_type(8)))  unsigned short u16x8;

typedef const __attribute__((address_space(1))) void* gp1;
typedef __attribute__((address_space(3))) void* lp3;
#define GLOAD16(g, l) __builtin_amdgcn_global_load_lds((gp1)(g), (lp3)(l), 16, 0, 0)

__device__ __forceinline__ u16 f2bf(float f) {
    union { float f; unsigned u; } c; c.f = f;
    unsigned r = c.u + 0x7fffu + ((c.u >> 16) & 1u);   // RNE
    return (u16)(r >> 16);
}

// ---------------- fp32 -> bf16 cast (all 5 arrays, one launch) ----------------
__global__ void castall(const float* __restrict__ x,  const float* __restrict__ wq,
                        const float* __restrict__ wk, const float* __restrict__ wv,
                        const float* __restrict__ wp,
                        u16* __restrict__ xb,  u16* __restrict__ wqb, u16* __restrict__ wkb,
                        u16* __restrict__ wvb, u16* __restrict__ wpb) {
    int blk = blockIdx.x;
    const float* src; u16* dst; long off;
    if (blk < 2048) { src = x; dst = xb; off = (long)blk * 1024; }
    else {
        int w = (blk - 2048) >> 9, bb = (blk - 2048) & 511;
        src = (w == 0 ? wq : w == 1 ? wk : w == 2 ? wv : wp);
        dst = (w == 0 ? wqb : w == 1 ? wkb : w == 2 ? wvb : wpb);
        off = (long)bb * 1024;
    }
    long i = off + threadIdx.x * 4;
    f32x4 v = *(const f32x4*)(src + i);
    u16x4 o;
    o[0] = f2bf(v[0]); o[1] = f2bf(v[1]); o[2] = f2bf(v[2]); o[3] = f2bf(v[3]);
    *(u16x4*)(dst + i) = o;
}

// ---------------- QKV projection GEMM ----------------
// M=8192, N=6144, K=256. BK=128, both-sides chunk-XOR swizzle (R14),
// V epilogue via LDS transpose bounce (R15, -3us). Q/K epilogues stay
// direct-store: their 32B-segmented patterns beat a scalar-LDS transpose
// (64 ds ops/thread ~ 7us of LDS pipe across the grid — worse than the
// current global stores; V won only because its pattern was 8B/80B scatter
// AND the readback stayed vectorized).
// Outputs:
// Q -> [B,H,S,256] linear bf16.
// K -> swizzled tile image: per bh, 32 tiles [32 rows(s)][256 cols(e)],
//      elem (r,c) at u16 idx r*256 + ((c&~7)^((r&7)<<3)) + (c&7).
// V -> PADDED tile image: per bh, 32 tiles [256 rows(e)][40 cols(j)], j<32 valid,
//      elem (e,j) at u16 idx e*40 + j.
__global__ __launch_bounds__(256) void qkv_gemm(
    const u16* __restrict__ xb,
    const u16* __restrict__ Wqb, const u16* __restrict__ Wkb, const u16* __restrict__ Wvb,
    const float* __restrict__ bq, const float* __restrict__ bk, const float* __restrict__ bv,
    u16* __restrict__ Qb, u16* __restrict__ Kimg, u16* __restrict__ Vimg)
{
    __shared__ u16 smem[32768];     // As [0,16384) | Bs [16384,32768); V bounce reuses
    u16* As = smem;                 // [128 m][16 chunks of 8 u16], chunk^row&7
    u16* Bs = smem + 16384;         // [128 n][16 chunks], chunk^row&7
    const int tid  = threadIdx.x;
    const int lane = tid & 63;
    const int li   = lane & 15, lg = lane >> 4;
    const int wave = tid >> 6;
    const int wr   = wave >> 1, wc = wave & 1;
    const int m0   = blockIdx.x * 128;
    const int n0g  = blockIdx.y * 128;
    const int w    = n0g >> 11;            // 0:Q 1:K 2:V
    const int h    = (n0g >> 8) & 7;
    const int e0   = n0g & 255;            // 0 or 128
    const u16* Wsel = (w == 0 ? Wqb : (w == 1 ? Wkb : Wvb)) + h * 65536;

    f32x4 acc[4][4] = {};

    for (int k0 = 0; k0 < 256; k0 += 128) {
        __syncthreads();
        #pragma unroll
        for (int p = 0; p < 8; ++p) {
            const int g = p * 256 + tid, row = g >> 4, cl = g & 15;
            const size_t soff = ((size_t)row) * 256 + k0 + ((cl ^ (row & 7)) * 8);
            GLOAD16(&xb[(size_t)m0 * 256 + soff],   &As[g * 8]);
            GLOAD16(&Wsel[(size_t)e0 * 256 + soff], &Bs[g * 8]);
        }
        __syncthreads();

        #pragma unroll
        for (int kk = 0; kk < 4; ++kk) {
            s16x8 af[4], bf[4];
            #pragma unroll
            for (int mi = 0; mi < 4; ++mi) {
                const int arow = wr * 64 + mi * 16 + li;
                af[mi] = *(const s16x8*)&As[arow * 128 + (((kk * 4 + lg) ^ (arow & 7)) * 8)];
            }
            #pragma unroll
            for (int ni = 0; ni < 4; ++ni) {
                const int brow = wc * 64 + ni * 16 + li;
                bf[ni] = *(const s16x8*)&Bs[brow * 128 + (((kk * 4 + lg) ^ (brow & 7)) * 8)];
            }
            #pragma unroll
            for (int mi = 0; mi < 4; ++mi)
                #pragma unroll
                for (int ni = 0; ni < 4; ++ni)
                    acc[mi][ni] = __builtin_amdgcn_mfma_f32_16x16x32_bf16(af[mi], bf[ni], acc[mi][ni], 0, 0, 0);
        }
    }

    const int b  = m0 >> 10;
    const int s0 = m0 & 1023;
    if (w == 0) {
        const float* bp = bq + 256 * h;
        #pragma unroll
        for (int ni = 0; ni < 4; ++ni) {
            const int e = e0 + wc * 64 + ni * 16 + li;
            const float bias = bp[e];
            u16* obase = Qb + ((size_t)(b * 8 + h)) * 1024 * 256 + e;
            #pragma unroll
            for (int mi = 0; mi < 4; ++mi)
                #pragma unroll
                for (int r = 0; r < 4; ++r) {
                    int s = s0 + wr * 64 + mi * 16 + lg * 4 + r;
                    obase[(size_t)s * 256] = f2bf(acc[mi][ni][r] + bias);
                }
        }
    } else if (w == 1) {
        const float* bp = bk + 256 * h;
        u16* kb = Kimg + ((size_t)(b * 8 + h)) * 262144;
        #pragma unroll
        for (int ni = 0; ni < 4; ++ni) {
            const int e = e0 + wc * 64 + ni * 16 + li;
            const float bias = bp[e];
            #pragma unroll
            for (int mi = 0; mi < 4; ++mi)
                #pragma unroll
                for (int r = 0; r < 4; ++r) {
                    int s = s0 + wr * 64 + mi * 16 + lg * 4 + r;
                    int t = s >> 5, rr = s & 31;
                    size_t idx = (size_t)t * 8192 + rr * 256
                               + (((e & ~7) ^ ((rr & 7) << 3)) | (e & 7));
                    kb[idx] = f2bf(acc[mi][ni][r] + bias);
                }
        }
    } else {
        // V: LDS transpose bounce (R15). Vt[128 e][132 s] u16.
        const float* bp = bv + 256 * h;
        u16* vb = Vimg + ((size_t)(b * 8 + h)) * 327680;
        const int t0 = s0 >> 5;
        u16* Vt = smem;
        __syncthreads();
        #pragma unroll
        for (int ni = 0; ni < 4; ++ni) {
            const int eloc = wc * 64 + ni * 16 + li;
            const float bias = bp[e0 + eloc];
            #pragma unroll
            for (int mi = 0; mi < 4; ++mi) {
                const int sloc = wr * 64 + mi * 16 + lg * 4;
                u16x4 pk;
                #pragma unroll
                for (int r = 0; r < 4; ++r) pk[r] = f2bf(acc[mi][ni][r] + bias);
                *(u16x4*)&Vt[eloc * 132 + sloc] = pk;
            }
        }
        __syncthreads();
        #pragma unroll
        for (int p = 0; p < 8; ++p) {
            const int g    = p * 256 + tid;
            const int eloc = g >> 4;
            const int tt   = (g >> 2) & 3;
            const int ch   = g & 3;
            const int sloc = tt * 32 + ch * 8;
            u16x8 v = *(const u16x8*)&Vt[eloc * 132 + sloc];
            *(u16x8*)&vb[(size_t)(t0 + tt) * 10240 + (size_t)(e0 + eloc) * 40 + ch * 8] = v;
        }
    }
}

// ---------------- flash attention ----------------
// EXACT R0/session-best structure (83us, proven across many runs). Frozen:
// six perturbations (R9 PV-lag, R10 2-block, R12 SM-first, R16 parity split,
// R17 V-swizzle, R18 chain split) were all neutral-or-worse — this schedule
// is a sharply-tuned latency-bound local optimum (every pipe <50% busy);
// escaping it needs a full co-designed rewrite, not increments.
// 256 blocks = 64 (b,h) * 4 q-blocks; 8 waves (512 thr), 1 block/CU (108KB LDS).
// TRIPLE-buffered K and V; role-split staging (waves 0-3 K: 4 loads/iter,
// waves 4-7 V: 5 loads/iter); counted vmcnt(8)/vmcnt(10) at top of iter;
// raw s_barrier. Ledger: iter i reads slot i%3 between barrier-A and
// barrier-B; stage after barrier-B targets slot (i+3)%3 == i%3 (just freed);
// clamped tail re-stage keeps the vmcnt count invariant.
__device__ __forceinline__ void softmax_pack(
    f32x16& sacc, float& m_run, float& l_run, f32x16* oacc,
    int hi, s16x8& paA, s16x8& paB)
{
    const float C = 0.09016844f;       // log2(e)/sqrt(256)
    const float THR = 16.0f;           // defer-max threshold (raw S units)
    float pm = -1e30f;
    #pragma unroll
    for (int r = 0; r < 16; ++r) pm = fmaxf(pm, sacc[r]);
    pm = fmaxf(pm, __shfl_xor(pm, 32));
    if (!__all(pm - m_run <= THR)) {   // rare
        const float mnew = fmaxf(m_run, pm);
        const float corr = __builtin_amdgcn_exp2f((m_run - mnew) * C);
        l_run *= corr;
        #pragma unroll
        for (int r = 0; r < 16; ++r) {
            float rc = __shfl(corr, (r & 3) + 8 * (r >> 2) + 4 * hi);
            #pragma unroll
            for (int et = 0; et < 8; ++et) oacc[et][r] *= rc;
        }
        m_run = mnew;
    }
    float psum = 0.f;
    #pragma unroll
    for (int r = 0; r < 16; ++r) {
        float p = __builtin_amdgcn_exp2f((sacc[r] - m_run) * C);
        psum += p;
        sacc[r] = p;
    }
    psum += __shfl_xor(psum, 32);
    l_run += psum;
    unsigned dwA[4], dwB[4];
    #pragma unroll
    for (int c = 0; c < 4; ++c) {
        asm("v_cvt_pk_bf16_f32 %0, %1, %2" : "=v"(dwA[c]) : "v"(sacc[4*c]),   "v"(sacc[4*c+1]));
        asm("v_cvt_pk_bf16_f32 %0, %1, %2" : "=v"(dwB[c]) : "v"(sacc[4*c+2]), "v"(sacc[4*c+3]));
    }
    {
        unsigned a0 = dwA[0], a1 = dwA[1], b0 = dwB[0], b1 = dwB[1];
        asm("v_permlane32_swap_b32 %0, %1" : "+v"(a0), "+v"(a1));
        asm("v_permlane32_swap_b32 %0, %1" : "+v"(b0), "+v"(b1));
        union { unsigned u[4]; s16x8 v; } pk;
        pk.u[0] = a0; pk.u[1] = b0; pk.u[2] = a1; pk.u[3] = b1;
        paA = pk.v;
    }
    {
        unsigned a0 = dwA[2], a1 = dwA[3], b0 = dwB[2], b1 = dwB[3];
        asm("v_permlane32_swap_b32 %0, %1" : "+v"(a0), "+v"(a1));
        asm("v_permlane32_swap_b32 %0, %1" : "+v"(b0), "+v"(b1));
        union { unsigned u[4]; s16x8 v; } pk;
        pk.u[0] = a0; pk.u[1] = b0; pk.u[2] = a1; pk.u[3] = b1;
        paB = pk.v;
    }
}

__global__ __launch_bounds__(512, 2) void attn(
    const u16* __restrict__ Qb, const u16* __restrict__ Kimg,
    const u16* __restrict__ Vimg, u16* __restrict__ Ob)
{
    __shared__ u16 kbuf[3][8192];      // [32 j][256 d] swizzled, 16KB each
    __shared__ u16 vbuf[3][10240];     // [256 e][40 j] padded, 20KB each
    const int tid  = threadIdx.x;
    const int lane = tid & 63;
    const int wave = tid >> 6;
    const int col  = lane & 31;        // q-row for S, e-col for O
    const int hi   = lane >> 5;
    const int hi8  = hi * 8;
    const int ksw  = (lane & 7) << 3;  // K-read XOR swizzle
    // XCD swizzle: 256 blocks, 32 per XCD -> 8 distinct (b,h) per XCD
    const int bid  = ((blockIdx.x & 7) << 5) | (blockIdx.x >> 3);
    const int bh   = bid >> 2;
    const int qblk = bid & 3;
    const int q0   = qblk * 256 + wave * 32;   // wave's 32 q-rows

    const u16* qp = Qb + ((size_t)bh * 1024 + q0) * 256;
    const u16* kg = Kimg + (size_t)bh * 262144;
    const u16* vg = Vimg + (size_t)bh * 327680;

    // capture-safe role-split stage: waves 0-3 -> K (4 loads), 4-7 -> V (5 loads)
    #define STAGE(sl, t)                                                          \
        {                                                                         \
            const int sl_ = (sl);                                                 \
            const int t_  = (t);                                                  \
            if (tid < 256) {                                                      \
                const size_t kb_ = (size_t)t_ * 8192 + tid * 8;                   \
                _Pragma("unroll")                                                 \
                for (int c_ = 0; c_ < 4; ++c_)                                    \
                    GLOAD16(&kg[kb_ + c_ * 2048], &kbuf[sl_][c_ * 2048 + tid * 8]); \
            } else {                                                              \
                const int    vt_ = tid - 256;                                     \
                const size_t vb_ = (size_t)t_ * 10240 + vt_ * 8;                  \
                _Pragma("unroll")                                                 \
                for (int c_ = 0; c_ < 5; ++c_)                                    \
                    GLOAD16(&vg[vb_ + c_ * 2048], &vbuf[sl_][c_ * 2048 + vt_ * 8]); \
            }                                                                     \
        }

    // Q B-frags first (their vmcnt retires before the batches we count against)
    s16x8 qf[16];
    #pragma unroll
    for (int dk = 0; dk < 16; ++dk)
        qf[dk] = *(const s16x8*)&qp[(size_t)col * 256 + dk * 16 + hi8];

    // prologue: 3 batches in flight
    STAGE(0, 0);
    STAGE(1, 1);
    STAGE(2, 2);

    f32x16 oacc[8] = {};               // O[q=crow(r,hi)][e=et*32+col]
    float m_run = -1e30f, l_run = 0.f;
    f32x16 sacc;
    s16x8 paA, paB;

    for (int i = 0; i < 32; ++i) {
        // counted wait: allow 2 newest batches in flight -> batch i resident
        if (tid < 256) { asm volatile("s_waitcnt vmcnt(8)"  ::: "memory"); }
        else           { asm volatile("s_waitcnt vmcnt(10)" ::: "memory"); }
        __builtin_amdgcn_s_barrier();              // barrier-A: whole tile i visible
        asm volatile("" ::: "memory");
        const int slot = i % 3;
        const u16* kt = kbuf[slot];
        const u16* vt = vbuf[slot];

        __builtin_amdgcn_s_setprio(1);
        {   // QK: S[j=crow(r,hi)][q=col]
            sacc = (f32x16){};
            const int rb_ = col * 256;
            #pragma unroll
            for (int dk_ = 0; dk_ < 16; ++dk_) {
                s16x8 kf = *(const s16x8*)&kt[rb_ + ((dk_ * 16 + hi8) ^ ksw)];
                sacc = __builtin_amdgcn_mfma_f32_32x32x16_bf16(kf, qf[dk_], sacc, 0, 0, 0);
            }
        }
        __builtin_amdgcn_s_setprio(0);

        softmax_pack(sacc, m_run, l_run, oacc, hi, paA, paB);

        __builtin_amdgcn_s_setprio(1);
        {   // PV
            #pragma unroll
            for (int et_ = 0; et_ < 8; ++et_) {
                s16x8 vf = *(const s16x8*)&vt[(et_ * 32 + col) * 40 + hi8];
                oacc[et_] = __builtin_amdgcn_mfma_f32_32x32x16_bf16(paA, vf, oacc[et_], 0, 0, 0);
            }
            #pragma unroll
            for (int et_ = 0; et_ < 8; ++et_) {
                s16x8 vf = *(const s16x8*)&vt[(et_ * 32 + col) * 40 + 16 + hi8];
                oacc[et_] = __builtin_amdgcn_mfma_f32_32x32x16_bf16(paB, vf, oacc[et_], 0, 0, 0);
            }
        }
        __builtin_amdgcn_s_setprio(0);

        asm volatile("" ::: "memory");
        __builtin_amdgcn_s_barrier();              // barrier-B: slot reads done
        asm volatile("" ::: "memory");
        const int nt = (i + 3 < 32) ? (i + 3) : 31;   // clamp keeps count invariant
        STAGE(slot, nt);                           // slot (i+3)%3 == i%3, just freed
    }
    #undef STAGE

    // normalize + store: Ob [B,S,H*256]
    const float linv = 1.0f / l_run;
    const int b = bh >> 3, h = bh & 7;
    u16* op = Ob + ((size_t)b * 1024) * 2048 + h * 256;
    #pragma unroll
    for (int r = 0; r < 16; ++r) {
        const int crow = (r & 3) + 8 * (r >> 2) + 4 * hi;
        float lr = __shfl(linv, crow);
        const size_t row = q0 + crow;
        #pragma unroll
        for (int et = 0; et < 8; ++et)
            op[row * 2048 + et * 32 + col] = f2bf(oacc[et][r] * lr);
    }
}

// ---------------- output projection ----------------
// out[m, n] = sum_k Ob[m, k] * Wp[n, k]; M=8192, N=256, K=2048; fp32 out.
// R13 (validated, -11us; R19's BM=64 variant was neutral-to-worse, reverted):
// BM=32/BN=128, BK=128, 16 iters x 16 MFMAs/wave/iter, 40KB LDS,
// both-sides chunk-XOR swizzle (cl ^ (row&7)). Grid (256,2) = 512 blocks.
__global__ __launch_bounds__(256) void out_gemm(
    const u16* __restrict__ Ob, const u16* __restrict__ Wpb, float* __restrict__ out)
{
    __shared__ u16 As[32 * 128];    // [32 m][16 chunks of 8 u16], chunk^row&7
    __shared__ u16 Bs[128 * 128];   // [128 n][16 chunks], chunk^row&7
    const int tid  = threadIdx.x;
    const int lane = tid & 63;
    const int li   = lane & 15, lg = lane >> 4;
    const int wave = tid >> 6;
    const int wr   = wave >> 1, wc = wave & 1;   // wave tile 16x64
    const int m0   = blockIdx.x * 32;
    const int n0   = blockIdx.y * 128;

    f32x4 acc[4] = {};

    for (int k0 = 0; k0 < 2048; k0 += 128) {
        __syncthreads();
        // stage A: 512 16B-chunks, 2 passes (source pre-swizzled, LDS linear)
        #pragma unroll
        for (int p = 0; p < 2; ++p) {
            const int g = p * 256 + tid, row = g >> 4, cl = g & 15;
            GLOAD16(&Ob[(size_t)(m0 + row) * 2048 + k0 + ((cl ^ (row & 7)) * 8)],
                    &As[g * 8]);
        }
        // stage B: 2048 chunks, 8 passes
        #pragma unroll
        for (int p = 0; p < 8; ++p) {
            const int g = p * 256 + tid, row = g >> 4, cl = g & 15;
            GLOAD16(&Wpb[(size_t)(n0 + row) * 2048 + k0 + ((cl ^ (row & 7)) * 8)],
                    &Bs[g * 8]);
        }
        __syncthreads();

        const int arow = wr * 16 + li;
        s16x8 af[4];
        #pragma unroll
        for (int kk = 0; kk < 4; ++kk)
            af[kk] = *(const s16x8*)&As[arow * 128 + (((kk * 4 + lg) ^ (arow & 7)) * 8)];
        #pragma unroll
        for (int ni = 0; ni < 4; ++ni) {
            const int brow = wc * 64 + ni * 16 + li;
            #pragma unroll
            for (int kk = 0; kk < 4; ++kk) {
                s16x8 bf = *(const s16x8*)&Bs[brow * 128 + (((kk * 4 + lg) ^ (brow & 7)) * 8)];
                acc[ni] = __builtin_amdgcn_mfma_f32_16x16x32_bf16(af[kk], bf, acc[ni], 0, 0, 0);
            }
        }
    }

    #pragma unroll
    for (int ni = 0; ni < 4; ++ni) {
        int n = n0 + wc * 64 + ni * 16 + li;
        #pragma unroll
        for (int r = 0; r < 4; ++r) {
            int m = m0 + wr * 16 + lg * 4 + r;
            out[(size_t)m * 256 + n] = acc[ni][r];
        }
    }
}

extern "C" void kernel_launch(void* const* d_in, const int* in_sizes, int n_in,
                              void* d_out, int out_size, void* d_ws, size_t ws_size,
                              hipStream_t stream) {
    const float* x  = (const float*)d_in[0];
    const float* Wq = (const float*)d_in[1];
    const float* Wk = (const float*)d_in[2];
    const float* Wv = (const float*)d_in[3];
    const float* bq = (const float*)d_in[4];
    const float* bk = (const float*)d_in[5];
    const float* bv = (const float*)d_in[6];
    const float* Wp = (const float*)d_in[7];
    float* out = (float*)d_out;

    u16* xb   = (u16*)d_ws;               // 2,097,152
    u16* Wqb  = xb   + (1u << 21);        // 524,288 each
    u16* Wkb  = Wqb  + (1u << 19);
    u16* Wvb  = Wkb  + (1u << 19);
    u16* Wpb  = Wvb  + (1u << 19);
    u16* Qb   = Wpb  + (1u << 19);        // 16,777,216
    u16* Kimg = Qb   + (1u << 24);        // 16,777,216
    u16* Vimg = Kimg + (1u << 24);        // 20,971,520 (padded V)
    u16* Ob   = Vimg + 20971520u;         // 16,777,216

    castall<<<4096, 256, 0, stream>>>(x, Wq, Wk, Wv, Wp, xb, Wqb, Wkb, Wvb, Wpb);
    qkv_gemm<<<dim3(64, 48), 256, 0, stream>>>(xb, Wqb, Wkb, Wvb, bq, bk, bv, Qb, Kimg, Vimg);
    attn<<<256, 512, 0, stream>>>(Qb, Kimg, Vimg, Ob);
    out_gemm<<<dim3(256, 2), 256, 0, stream>>>(Ob, Wpb, out);
}